// Round 4
// baseline (286.353 us; speedup 1.0000x reference)
//
#include <hip/hip_runtime.h>

typedef unsigned short u16;
typedef __bf16 bf16x8 __attribute__((ext_vector_type(8)));
typedef float f32x4 __attribute__((ext_vector_type(4)));
typedef unsigned short u16x8 __attribute__((ext_vector_type(8)));
typedef unsigned short u16x4 __attribute__((ext_vector_type(4)));

#define NPIX 25088
#define HW 3136

static __device__ __forceinline__ u16 f2bf(float f) {
  // round-to-nearest-even f32 -> bf16 (no NaN/inf in this workload)
  unsigned u = __builtin_bit_cast(unsigned, f);
  return (u16)((u + 0x7fffu + ((u >> 16) & 1u)) >> 16);
}

// ---------------------------------------------------------------------------
// Wpb layout (c-slice-major, XOR-swizzled at 16-byte granularity):
//   slice c occupies u16 range [c*16384, (c+1)*16384)  (32 KB per slice)
//   within a slice: element (o, d) lives at
//     o*64 + (((d>>3) ^ (o&7)) << 3) + (d&7)
// The swizzle makes the bilinear kernel's ds_read_b128 B-fragment reads
// bank-balanced (8-cycle floor) while staging remains a LINEAR 32 KB copy.
// ---------------------------------------------------------------------------

// ---------------------------------------------------------------------------
// Kernel 1: blocks [0,98)   -> p1 = W1 @ x1 per pixel, stored fp32 transposed P1T[c][pixel]
//           blocks [98,196) -> p2 = W2 @ x2 per pixel, stored bf16 P2b[pixel][d]
//           blocks [196,708)-> Wp fp32 -> bf16, swizzled slice-major layout (above)
// Weights are wave-uniform -> scalar loads; per-pixel x held in VGPRs.
// ---------------------------------------------------------------------------
__global__ __launch_bounds__(256, 2) void proj_kernel(
    const float* __restrict__ x1, const float* __restrict__ x2,
    const float* __restrict__ W1, const float* __restrict__ W2,
    const float* __restrict__ Wp,
    float* __restrict__ P1T, u16* __restrict__ P2b, u16* __restrict__ Wpb)
{
  const int blk = blockIdx.x;
  const int t = threadIdx.x;

  if (blk >= 196) {  // Wp conversion: 512 blocks * 256 thr * 8 elems = 1048576
    const long e = (long)(blk - 196) * 2048 + (long)t * 8;  // [o][c][d] linear
    f32x4 a = *(const f32x4*)(Wp + e);
    f32x4 b = *(const f32x4*)(Wp + e + 4);
    u16x8 v;
    v[0]=f2bf(a[0]); v[1]=f2bf(a[1]); v[2]=f2bf(a[2]); v[3]=f2bf(a[3]);
    v[4]=f2bf(b[0]); v[5]=f2bf(b[1]); v[6]=f2bf(b[2]); v[7]=f2bf(b[3]);
    const int o  = (int)(e >> 12);
    const int c  = (int)(e >> 6) & 63;
    const int j  = (int)(e >> 3) & 7;          // 16-B chunk index within o-row
    const int dst = c * 16384 + o * 64 + ((j ^ (o & 7)) << 3);
    *(u16x8*)(Wpb + dst) = v;
    return;
  }

  const bool isP1 = blk < 98;
  const float* __restrict__ x = isP1 ? x1 : x2;
  const float* __restrict__ W = isP1 ? W1 : W2;  // block-uniform -> scalar

  const int p = (isP1 ? blk : blk - 98) * 256 + t;   // one pixel per thread
  const int b = p / HW;
  const int hw = p - b * HW;
  const float* xp = x + (size_t)b * 128 * HW + hw;

  // all 128 channel values of this pixel in registers (coalesced loads)
  float xr[128];
  #pragma unroll
  for (int c = 0; c < 128; ++c) xr[c] = xp[(size_t)c * HW];

  #pragma unroll 1
  for (int mq = 0; mq < 16; ++mq) {
    const float* Wr = W + mq * 4 * 128;   // 4 output rows, wave-uniform
    float a0 = 0.f, a1 = 0.f, a2 = 0.f, a3 = 0.f;
    #pragma unroll
    for (int c = 0; c < 128; ++c) {
      const float xv = xr[c];
      a0 = fmaf(Wr[c],       xv, a0);
      a1 = fmaf(Wr[128 + c], xv, a1);
      a2 = fmaf(Wr[256 + c], xv, a2);
      a3 = fmaf(Wr[384 + c], xv, a3);
    }
    if (isP1) {
      P1T[(size_t)(mq * 4 + 0) * NPIX + p] = a0;
      P1T[(size_t)(mq * 4 + 1) * NPIX + p] = a1;
      P1T[(size_t)(mq * 4 + 2) * NPIX + p] = a2;
      P1T[(size_t)(mq * 4 + 3) * NPIX + p] = a3;
    } else {
      u16x4 v;
      v[0] = f2bf(a0); v[1] = f2bf(a1); v[2] = f2bf(a2); v[3] = f2bf(a3);
      *(u16x4*)(P2b + (size_t)p * 64 + mq * 4) = v;
    }
  }
}

// ---------------------------------------------------------------------------
// Kernel 2: per block: 64 pixels x 256 outputs. 8 waves, wave w owns o in [w*32,+32).
// Double-buffered LDS staging of the 32 KB Wp c-slice (reg-staged, T14
// issue-early/write-late), one __syncthreads per c-step. All waits are
// compiler-managed -> correctness-robust. B-fragments via swizzled ds_read_b128.
// Epilogue: fused LayerNorm + erf-GELU + LDS transpose, coalesced NCHW store.
// ---------------------------------------------------------------------------
__global__ __launch_bounds__(512, 2) void bilinear_kernel(
    const float* __restrict__ P1T, const u16* __restrict__ P2b,
    const u16* __restrict__ Wpb, const float* __restrict__ gamma,
    const float* __restrict__ beta, float* __restrict__ out)
{
  __shared__ __align__(16) unsigned char smem[94208];
  u16*   P2s  = (u16*)smem;               // [64 pix][64 d] bf16      0 ..  8192
  float* P1Ts = (float*)(smem + 8192);    // [64 c][64 pix] f32    8192 .. 24576
  u16*   Bbuf = (u16*)(smem + 24576);     // 2 x 32768 B          24576 .. 90112
  float* tbuf = (float*)smem;             // epilogue alias           0 .. 33280
  float* ssum = (float*)(smem + 90112);   // [64 pix][8 w]
  float* ssq  = (float*)(smem + 92160);   // [64 pix][8 w]

  const int t = threadIdx.x;
  const int w = t >> 6;
  const int lane = t & 63;
  const int l15 = lane & 15;
  const int l4 = lane >> 4;
  const int P0 = blockIdx.x * 64;

  // ---- stage P2 tile (bf16) + P1T tile (f32) + B slice 0 into LDS
  {
    const int row = t >> 3;
    const int col = (t & 7) * 8;
    *(u16x8*)&P2s[row * 64 + col] = *(const u16x8*)(P2b + (long)(P0 + row) * 64 + col);
    const float* src = P1T + (long)row * NPIX + P0 + col;
    *(f32x4*)&P1Ts[row * 64 + col]     = *(const f32x4*)src;
    *(f32x4*)&P1Ts[row * 64 + col + 4] = *(const f32x4*)(src + 4);
    #pragma unroll
    for (int r = 0; r < 4; ++r)   // linear 32 KB copy, coalesced, bank-ideal
      *(u16x8*)&Bbuf[r * 4096 + t * 8] = *(const u16x8*)(Wpb + r * 4096 + t * 8);
  }
  __syncthreads();

  // ---- A fragments (p2), loaded ONCE, reused across all 64 c-slices
  // A layout: row(pixel)=l15, k = ks*32 + l4*8 + j
  bf16x8 afr[4][2];
  #pragma unroll
  for (int m = 0; m < 4; ++m)
    #pragma unroll
    for (int ks = 0; ks < 2; ++ks)
      afr[m][ks] = __builtin_bit_cast(bf16x8,
          *(const u16x8*)&P2s[(m * 16 + l15) * 64 + ks * 32 + l4 * 8]);

  // ---- B-fragment LDS indices (u16 units, constant across the loop)
  // col(o) = w*32 + n*16 + l15; chunk = ks*4 + l4, XOR-swizzled by (o&7)
  unsigned bofs[2][2];
  #pragma unroll
  for (int n = 0; n < 2; ++n) {
    const int o = w * 32 + n * 16 + l15;
    #pragma unroll
    for (int ks = 0; ks < 2; ++ks)
      bofs[n][ks] = (unsigned)(o * 64 + (((ks * 4 + l4) ^ (o & 7)) << 3));
  }

  const f32x4 zero4 = {0.f, 0.f, 0.f, 0.f};
  f32x4 acc[4][2];
  #pragma unroll
  for (int m = 0; m < 4; ++m)
    #pragma unroll
    for (int n = 0; n < 2; ++n) acc[m][n] = zero4;

  u16x8 sreg[4];

  #pragma unroll 2
  for (int c = 0; c < 64; ++c) {
    // (a) issue next slice's global loads early -- overlap with compute below
    if (c < 63) {
      const u16* src = Wpb + (c + 1) * 16384;
      #pragma unroll
      for (int r = 0; r < 4; ++r)
        sreg[r] = *(const u16x8*)(src + r * 4096 + t * 8);
    }

    // (b) compute slice c from Bbuf[c&1]
    const u16* Bcur = Bbuf + (c & 1) * 16384;
    f32x4 p1v[4];
    #pragma unroll
    for (int m = 0; m < 4; ++m)
      p1v[m] = *(const f32x4*)&P1Ts[c * 64 + m * 16 + l4 * 4];

    bf16x8 bf[2][2];
    #pragma unroll
    for (int n = 0; n < 2; ++n)
      #pragma unroll
      for (int ks = 0; ks < 2; ++ks)
        bf[n][ks] = __builtin_bit_cast(bf16x8, *(const u16x8*)&Bcur[bofs[n][ks]]);

    #pragma unroll
    for (int m = 0; m < 4; ++m) {
      f32x4 s0 = zero4, s1 = zero4;
      s0 = __builtin_amdgcn_mfma_f32_16x16x32_bf16(afr[m][0], bf[0][0], s0, 0, 0, 0);
      s0 = __builtin_amdgcn_mfma_f32_16x16x32_bf16(afr[m][1], bf[0][1], s0, 0, 0, 0);
      s1 = __builtin_amdgcn_mfma_f32_16x16x32_bf16(afr[m][0], bf[1][0], s1, 0, 0, 0);
      s1 = __builtin_amdgcn_mfma_f32_16x16x32_bf16(afr[m][1], bf[1][1], s1, 0, 0, 0);
      #pragma unroll
      for (int r = 0; r < 4; ++r) {
        acc[m][0][r] = fmaf(p1v[m][r], s0[r], acc[m][0][r]);
        acc[m][1][r] = fmaf(p1v[m][r], s1[r], acc[m][1][r]);
      }
    }

    // (c) write next slice into the other buffer, then one barrier per step
    if (c < 63) {
      u16* dst = Bbuf + ((c + 1) & 1) * 16384;
      #pragma unroll
      for (int r = 0; r < 4; ++r)
        *(u16x8*)&dst[r * 4096 + t * 8] = sreg[r];
    }
    __syncthreads();
  }

  // ---- LayerNorm stats: per-lane partials over this wave's 32 o's
  float psum[4][4], psq[4][4];
  #pragma unroll
  for (int m = 0; m < 4; ++m)
    #pragma unroll
    for (int r = 0; r < 4; ++r) {
      float a0 = acc[m][0][r], a1 = acc[m][1][r];
      psum[m][r] = a0 + a1;
      psq[m][r]  = a0 * a0 + a1 * a1;
    }
  #pragma unroll
  for (int mask = 1; mask < 16; mask <<= 1) {
    #pragma unroll
    for (int m = 0; m < 4; ++m)
      #pragma unroll
      for (int r = 0; r < 4; ++r) {
        psum[m][r] += __shfl_xor(psum[m][r], mask);
        psq[m][r]  += __shfl_xor(psq[m][r], mask);
      }
  }
  if (l15 == 0) {
    #pragma unroll
    for (int m = 0; m < 4; ++m)
      #pragma unroll
      for (int r = 0; r < 4; ++r) {
        const int pix = m * 16 + l4 * 4 + r;
        ssum[pix * 8 + w] = psum[m][r];
        ssq[pix * 8 + w]  = psq[m][r];
      }
  }
  __syncthreads();

  float mean[4][4], rstd[4][4];
  #pragma unroll
  for (int m = 0; m < 4; ++m)
    #pragma unroll
    for (int r = 0; r < 4; ++r) {
      const int pix = m * 16 + l4 * 4 + r;
      float s = 0.f, q = 0.f;
      #pragma unroll
      for (int wv = 0; wv < 8; ++wv) { s += ssum[pix * 8 + wv]; q += ssq[pix * 8 + wv]; }
      float mu = s * (1.f / 256.f);
      float var = q * (1.f / 256.f) - mu * mu;
      mean[m][r] = mu;
      rstd[m][r] = rsqrtf(var + 1e-5f);
    }

  const int bidx = P0 / HW;
  const int hw0 = P0 - bidx * HW;
  float gam[2], bet[2];
  #pragma unroll
  for (int n = 0; n < 2; ++n) {
    gam[n] = gamma[w * 32 + n * 16 + l15];
    bet[n] = beta[w * 32 + n * 16 + l15];
  }

  // ---- normalize + erf-GELU + transpose via LDS for coalesced NCHW stores
  #pragma unroll
  for (int n = 0; n < 2; ++n) {
    __syncthreads();
    #pragma unroll
    for (int m = 0; m < 4; ++m)
      #pragma unroll
      for (int r = 0; r < 4; ++r) {
        float v = (acc[m][n][r] - mean[m][r]) * rstd[m][r];
        v = v * gam[n] + bet[n];
        float ge = 0.5f * v * (1.f + erff(v * 0.70710678f));
        tbuf[w * 1040 + l15 * 65 + m * 16 + l4 * 4 + r] = ge;
      }
    __syncthreads();
    #pragma unroll
    for (int row = 0; row < 16; ++row) {
      float v = tbuf[w * 1040 + row * 65 + lane];
      const int o = w * 32 + n * 16 + row;
      out[(long)bidx * 802816 + (long)o * HW + hw0 + lane] = v;
    }
  }
}

// ---------------------------------------------------------------------------
extern "C" void kernel_launch(void* const* d_in, const int* in_sizes, int n_in,
                              void* d_out, int out_size, void* d_ws, size_t ws_size,
                              hipStream_t stream) {
  const float* x1    = (const float*)d_in[0];
  const float* x2    = (const float*)d_in[1];
  const float* W1    = (const float*)d_in[2];
  const float* W2    = (const float*)d_in[3];
  const float* Wp    = (const float*)d_in[4];
  const float* gamma = (const float*)d_in[5];
  const float* beta  = (const float*)d_in[6];
  float* out = (float*)d_out;

  // workspace layout
  float* P1T = (float*)d_ws;                          // 64 x 25088 f32 = 6,422,528 B
  u16*   P2b = (u16*)((char*)d_ws + 6422528);         // 25088 x 64 bf16 = 3,211,264 B
  u16*   Wpb = (u16*)((char*)d_ws + 9633792);         // 64 slices x 32 KB = 2,097,152 B
  proj_kernel<<<dim3(708), dim3(256), 0, stream>>>(x1, x2, W1, W2, Wp, P1T, P2b, Wpb);
  bilinear_kernel<<<dim3(392), dim3(512), 0, stream>>>(P1T, P2b, Wpb, gamma, beta, out);
}